// Round 9
// baseline (569.483 us; speedup 1.0000x reference)
//
#include <hip/hip_runtime.h>

#define S_LEN 4096
#define D_DIM 64
#define NEG_BIG 1.0e15f
#define NC1 8          // k-chunks (8 tiles each)
#define SSTAT (8 * 64 * NC1 * 64)           // floats: [b][qt][kc][64] row partial sums
#define NPAD_OFF SSTAT                      // [0..7]=npadTot, [8..15]=firstNonPad
#define FLAGS_OFF (NPAD_OFF + 16)           // 512 ints: per-(b,qt) stats completion count
#define QCNT_OFF (FLAGS_OFF + 512)          // 8 ints: per-XCD ticket counters
#define WS_FLOATS_NEEDED (QCNT_OFF + 8)
#define VSTRIDE 70     // odd word-stride: transpose u16 writes ~conflict-free

typedef __bf16 bf16_t;
typedef bf16_t bf16x8 __attribute__((ext_vector_type(8)));
typedef bf16_t bf16x4v __attribute__((ext_vector_type(4)));
typedef bf16_t bf16x2v __attribute__((ext_vector_type(2)));
typedef float f32x4v __attribute__((ext_vector_type(4)));

// ---------------- kernel 0: prep — npad stats, zero flags + queue counters ----
__global__ void sdpa_prep(const float* __restrict__ Pg, float* __restrict__ ws)
{
    __shared__ float red[16];
    const int b   = blockIdx.x;          // 8 blocks
    const int tid = threadIdx.x;
    int* flags = (int*)(ws + FLAGS_OFF);
    if (tid < 64) flags[b * 64 + tid] = 0;
    if (tid == 128) ((int*)(ws + QCNT_OFF))[b] = 0;

    float cnt = 0.f, first = (float)S_LEN;
    const float* pb = Pg + (size_t)b * S_LEN;
    for (int i = tid; i < S_LEN; i += 256) {
        float p = pb[i];
        cnt += 1.f - p;
        if (p == 0.f) first = fminf(first, (float)i);
    }
    #pragma unroll
    for (int off = 32; off >= 1; off >>= 1) {
        cnt += __shfl_down(cnt, off);
        first = fminf(first, __shfl_down(first, off));
    }
    const int w = tid >> 6, lane = tid & 63;
    if (lane == 0) { red[w] = cnt; red[8 + w] = first; }
    __syncthreads();
    if (tid == 0) {
        ws[NPAD_OFF + b]     = red[0] + red[1] + red[2] + red[3];
        ws[NPAD_OFF + 8 + b] = fminf(fminf(red[8], red[9]), fminf(red[10], red[11]));
    }
}

// ---------------- kernel 1: merged stats ∥ W+PV, per-XCD work queues ----------
// Queue q (= batch q) tickets: [0,512) stats chunks, [512,1024) W+PV chunks,
// both qt-descending. Blocks claim from their own XCD's queue (L2 affinity),
// stealing from others only on exhaustion (correct under any dispatch).
__global__ __launch_bounds__(256, 2)
void sdpa_main(const float* __restrict__ Qg,
               const float* __restrict__ Kg,
               const float* __restrict__ Vg,
               const float* __restrict__ Pg,
               float* __restrict__ Wg,
               float* __restrict__ ws,
               float* __restrict__ ctx)
{
    __shared__ __align__(16) bf16_t Ks[64][72];
    __shared__ __align__(16) bf16_t VT[64][VSTRIDE];   // VT[d][k_local]
    __shared__ __align__(16) bf16_t Pf[64][72];        // bf16 weights; per-wave rows only
    __shared__ float pads[64];
    __shared__ float Lrow[64];
    __shared__ int   sB, sT;

    const int tid  = threadIdx.x;
    const int w    = tid >> 6;
    const int lane = tid & 63;
    const int g    = lane >> 4;
    const int c    = lane & 15;

    int* flags = (int*)(ws + FLAGS_OFF);
    int* qcnt  = (int*)(ws + QCNT_OFF);

    if (tid == 0) {
        int xcd;
        asm volatile("s_getreg_b32 %0, hwreg(HW_REG_XCC_ID)" : "=s"(xcd));
        int qb = -1, qt_ = -1;
        #pragma unroll 1
        for (int p = 0; p < 8; ++p) {
            int qq = (xcd + p) & 7;
            int tt = atomicAdd(qcnt + qq, 1);
            if (tt < 1024) { qb = qq; qt_ = tt; break; }
        }
        sB = qb; sT = qt_;
    }
    __syncthreads();
    const int b = sB;
    const int tk = sT;
    if (b < 0) return;                  // all work claimed (proof: can't happen)

    if (tk < 512) {
        // ================= STATS chunk =================
        const int qt = 63 - (tk >> 3);
        const int kc = tk & 7;
        const int q0 = qt * 64;
        const int bqt = b * 64 + qt;
        const size_t soff = ((size_t)(bqt * NC1 + kc)) * 64;

        if (kc == 0) {                  // zero this q-tile's ctx rows (before flag!)
            f32x4v z = {0.f, 0.f, 0.f, 0.f};
            float* cb = ctx + ((size_t)b * S_LEN + q0) * D_DIM;
            #pragma unroll
            for (int i = 0; i < 4; ++i)
                *(f32x4v*)(cb + i * 1024 + tid * 4) = z;
        }

        if (kc * 8 > qt) {              // trivial: chunk entirely future
            if (tid < 64) ws[soff + tid] = 0.f;
            __syncthreads();
            if (tid == 0) { __threadfence(); atomicAdd(flags + bqt, 1); }
            return;
        }

        bf16x8 qa[2];
        {
            const float* qrow = Qg + ((size_t)b * S_LEN + q0 + 16 * w + c) * D_DIM;
            #pragma unroll
            for (int ks = 0; ks < 2; ++ks) {
                float4 a0 = *(const float4*)(qrow + ks * 32 + 8 * g);
                float4 a1 = *(const float4*)(qrow + ks * 32 + 8 * g + 4);
                qa[ks][0]=(bf16_t)a0.x; qa[ks][1]=(bf16_t)a0.y; qa[ks][2]=(bf16_t)a0.z; qa[ks][3]=(bf16_t)a0.w;
                qa[ks][4]=(bf16_t)a1.x; qa[ks][5]=(bf16_t)a1.y; qa[ks][6]=(bf16_t)a1.z; qa[ks][7]=(bf16_t)a1.w;
            }
        }

        float l[4] = {0.f, 0.f, 0.f, 0.f};
        const int qgBase = q0 + 16 * w + 4 * g;
        const int kend = min(kc * 8 + 8, qt + 1);

        for (int kt = kc * 8; kt < kend; ++kt) {
            const int k0 = kt * 64;
            {
                const float* src = Kg + ((size_t)b * S_LEN + k0) * D_DIM;
                #pragma unroll
                for (int i = 0; i < 4; ++i) {
                    int f4 = i * 256 + tid;
                    int r  = f4 >> 4;
                    int c4 = (f4 & 15) * 4;
                    float4 v4 = *(const float4*)(src + (size_t)f4 * 4);
                    bf16x4v bv;
                    bv[0]=(bf16_t)v4.x; bv[1]=(bf16_t)v4.y; bv[2]=(bf16_t)v4.z; bv[3]=(bf16_t)v4.w;
                    *(bf16x4v*)&Ks[r][c4] = bv;
                }
                if (tid < 64) pads[tid] = Pg[(size_t)b * S_LEN + k0 + tid] * (-NEG_BIG);
            }
            __syncthreads();

            f32x4v sc[4];
            #pragma unroll
            for (int ct = 0; ct < 4; ++ct) {
                sc[ct] = (f32x4v){0.f, 0.f, 0.f, 0.f};
                #pragma unroll
                for (int ks = 0; ks < 2; ++ks) {
                    bf16x8 kb = *(const bf16x8*)&Ks[ct * 16 + c][ks * 32 + 8 * g];
                    sc[ct] = __builtin_amdgcn_mfma_f32_16x16x32_bf16(qa[ks], kb, sc[ct], 0, 0, 0);
                }
            }
            // deferred reduce: accumulate per-lane partials, shuffle-reduce once at end
            #pragma unroll
            for (int ct = 0; ct < 4; ++ct) {
                float pn  = pads[ct * 16 + c];
                int   kgi = k0 + ct * 16 + c;
                #pragma unroll
                for (int r = 0; r < 4; ++r) {
                    float lg = sc[ct][r] * 0.125f + pn;
                    if (kgi > qgBase + r) lg -= NEG_BIG;
                    l[r] += __expf(lg);
                }
            }
            __syncthreads();
        }

        #pragma unroll
        for (int r = 0; r < 4; ++r) {
            float s = l[r];
            s += __shfl_xor(s, 1);
            s += __shfl_xor(s, 2);
            s += __shfl_xor(s, 4);
            s += __shfl_xor(s, 8);
            l[r] = s;
        }
        if (c == 0) {
            #pragma unroll
            for (int r = 0; r < 4; ++r)
                ws[soff + 16 * w + 4 * g + r] = l[r];
        }
        __syncthreads();
        if (tid == 0) { __threadfence(); atomicAdd(flags + bqt, 1); }
        return;
    }

    // ================= W+PV chunk =================
    const int jt = tk - 512;
    const int qt = 63 - (jt >> 3);
    const int kc = jt & 7;
    const int q0 = qt * 64;
    const int kstart = kc * 8;
    const int bqt = b * 64 + qt;

    const float npadTot = ws[NPAD_OFF + b];
    const float firstNP = ws[NPAD_OFF + 8 + b];
    const bool  blockDeg = ((float)q0 < firstNP);

    float* wchunk = Wg + (size_t)b * S_LEN * S_LEN + (size_t)q0 * S_LEN;

    if (kstart > qt && !blockDeg) {
        // entire chunk strictly future, no degenerate rows: zeros, no spin needed
        const f32x4v z = {0.f, 0.f, 0.f, 0.f};
        for (int kt = kstart; kt < kstart + 8; ++kt) {
            float* wbase = wchunk + kt * 64;
            #pragma unroll
            for (int i = 0; i < 4; ++i) {
                int f4 = i * 256 + tid;
                int r  = f4 >> 4;
                int c4 = (f4 & 15) * 4;
                __builtin_nontemporal_store(z, (f32x4v*)(wbase + (size_t)r * S_LEN + c4));
            }
        }
        return;
    }

    // wait for all 8 stats chunks of this (b,qt) — each is running or done
    if (tid == 0) {
        int* fl = flags + bqt;
        while (__hip_atomic_load(fl, __ATOMIC_ACQUIRE, __HIP_MEMORY_SCOPE_AGENT) != 8)
            __builtin_amdgcn_s_sleep(2);
    }
    __syncthreads();
    __threadfence();

    // combine partial denominators (deg rows: closed-form count)
    if (tid < 64) {
        int qrow = q0 + tid;
        float L;
        if ((float)qrow < firstNP) {
            L = (float)(qrow + 1) + npadTot;
        } else {
            const float* sb = ws + (size_t)bqt * NC1 * 64 + tid;
            L = 0.f;
            const int need = (qt >> 3) + 1;
            for (int i = 0; i < need; ++i) L += sb[(size_t)i * 64];
        }
        Lrow[tid] = 1.f / L;
    }
    __syncthreads();

    bf16x8 qa[2];
    {
        const float* qrow = Qg + ((size_t)b * S_LEN + q0 + 16 * w + c) * D_DIM;
        #pragma unroll
        for (int ks = 0; ks < 2; ++ks) {
            float4 a0 = *(const float4*)(qrow + ks * 32 + 8 * g);
            float4 a1 = *(const float4*)(qrow + ks * 32 + 8 * g + 4);
            qa[ks][0]=(bf16_t)a0.x; qa[ks][1]=(bf16_t)a0.y; qa[ks][2]=(bf16_t)a0.z; qa[ks][3]=(bf16_t)a0.w;
            qa[ks][4]=(bf16_t)a1.x; qa[ks][5]=(bf16_t)a1.y; qa[ks][6]=(bf16_t)a1.z; qa[ks][7]=(bf16_t)a1.w;
        }
    }

    const int qgBase = q0 + 16 * w + 4 * g;
    float linv[4];
    #pragma unroll
    for (int r = 0; r < 4; ++r) linv[r] = Lrow[16 * w + 4 * g + r];

    f32x4v o[4];
    #pragma unroll
    for (int dt = 0; dt < 4; ++dt) o[dt] = (f32x4v){0.f, 0.f, 0.f, 0.f};

    for (int kt = kstart; kt < kstart + 8; ++kt) {
        const int k0 = kt * 64;
        float* wbase = wchunk + k0;
        const bool cur = (kt <= qt) || blockDeg;

        if (cur) {
            const float* ksrc = Kg + ((size_t)b * S_LEN + k0) * D_DIM;
            const float* vsrc = Vg + ((size_t)b * S_LEN + k0) * D_DIM;
            #pragma unroll
            for (int i = 0; i < 4; ++i) {
                int f4 = i * 256 + tid;
                int r  = f4 >> 4;
                int c4 = (f4 & 15) * 4;
                float4 kv = *(const float4*)(ksrc + (size_t)f4 * 4);
                bf16x4v bv;
                bv[0]=(bf16_t)kv.x; bv[1]=(bf16_t)kv.y; bv[2]=(bf16_t)kv.z; bv[3]=(bf16_t)kv.w;
                *(bf16x4v*)&Ks[r][c4] = bv;
                float4 vv = *(const float4*)(vsrc + (size_t)f4 * 4);
                VT[c4 + 0][r] = (bf16_t)vv.x;
                VT[c4 + 1][r] = (bf16_t)vv.y;
                VT[c4 + 2][r] = (bf16_t)vv.z;
                VT[c4 + 3][r] = (bf16_t)vv.w;
            }
            if (tid < 64) pads[tid] = Pg[(size_t)b * S_LEN + k0 + tid] * (-NEG_BIG);
            __syncthreads();

            f32x4v sc[4];
            #pragma unroll
            for (int ct = 0; ct < 4; ++ct) {
                sc[ct] = (f32x4v){0.f, 0.f, 0.f, 0.f};
                #pragma unroll
                for (int ks = 0; ks < 2; ++ks) {
                    bf16x8 kb = *(const bf16x8*)&Ks[ct * 16 + c][ks * 32 + 8 * g];
                    sc[ct] = __builtin_amdgcn_mfma_f32_16x16x32_bf16(qa[ks], kb, sc[ct], 0, 0, 0);
                }
            }
            if (!blockDeg) {
                #pragma unroll
                for (int ct = 0; ct < 4; ++ct) {
                    float pn  = pads[ct * 16 + c];
                    int   kgi = k0 + ct * 16 + c;
                    #pragma unroll
                    for (int r = 0; r < 4; ++r) {
                        float lg = sc[ct][r] * 0.125f + pn;
                        if (kgi > qgBase + r) lg -= NEG_BIG;
                        float wv = __expf(lg) * linv[r];        // == ref weight
                        __builtin_nontemporal_store(wv,
                            wbase + (size_t)(16 * w + 4 * g + r) * S_LEN + ct * 16 + c);
                        Pf[16 * w + 4 * g + r][ct * 16 + c] = (bf16_t)wv;
                    }
                }
            } else {
                #pragma unroll
                for (int ct = 0; ct < 4; ++ct) {
                    float pn  = pads[ct * 16 + c];
                    int   kgi = k0 + ct * 16 + c;
                    #pragma unroll
                    for (int r = 0; r < 4; ++r) {
                        float lg = sc[ct][r] * 0.125f + pn;
                        if (kgi > qgBase + r) lg -= NEG_BIG;
                        float wv = __expf(lg) * linv[r];
                        if ((float)(qgBase + r) < firstNP)      // degenerate row
                            wv = (kgi <= qgBase + r || pn == 0.f) ? linv[r] : 0.f;
                        __builtin_nontemporal_store(wv,
                            wbase + (size_t)(16 * w + 4 * g + r) * S_LEN + ct * 16 + c);
                        Pf[16 * w + 4 * g + r][ct * 16 + c] = (bf16_t)wv;
                    }
                }
            }
            // NO barrier: wave w reads only its own Pf rows (lgkmcnt orders within-wave);
            // VT covered by post-stage barrier. W-store drain overlaps PV MFMAs.

            #pragma unroll
            for (int ks = 0; ks < 2; ++ks) {
                bf16x8 wa = *(const bf16x8*)&Pf[16 * w + c][ks * 32 + 8 * g];
                #pragma unroll
                for (int dt = 0; dt < 4; ++dt) {
                    bf16x8 vb;
                    #pragma unroll
                    for (int p = 0; p < 4; ++p)
                        ((bf16x2v*)&vb)[p] = *(const bf16x2v*)&VT[dt * 16 + c][ks * 32 + 8 * g + 2 * p];
                    o[dt] = __builtin_amdgcn_mfma_f32_16x16x32_bf16(wa, vb, o[dt], 0, 0, 0);
                }
            }
            __syncthreads();   // protect Ks/VT/Pf before next-tile staging
        } else {
            const f32x4v z = {0.f, 0.f, 0.f, 0.f};
            #pragma unroll
            for (int i = 0; i < 4; ++i) {
                int f4 = i * 256 + tid;
                int r  = f4 >> 4;
                int c4 = (f4 & 15) * 4;
                __builtin_nontemporal_store(z, (f32x4v*)(wbase + (size_t)r * S_LEN + c4));
            }
        }
    }

    // accumulate partial PV straight into ctx (zeroed by kc==0 stats chunk)
    #pragma unroll
    for (int dt = 0; dt < 4; ++dt)
        #pragma unroll
        for (int r = 0; r < 4; ++r)
            atomicAdd(&ctx[((size_t)b * S_LEN + (q0 + 16 * w + 4 * g + r)) * D_DIM + dt * 16 + c],
                      o[dt][r]);
}

// ---------------- fallback: monolithic kernel (used only if ws too small) ----
__global__ __launch_bounds__(256, 2)
void sdpa_fused(const float* __restrict__ Qg,
                const float* __restrict__ Kg,
                const float* __restrict__ Vg,
                const float* __restrict__ Pg,
                float* __restrict__ Og,
                float* __restrict__ Wg)
{
    __shared__ __align__(16) bf16_t Qs[64][72];
    __shared__ __align__(16) bf16_t Ks[64][72];
    __shared__ __align__(16) bf16_t VT[64][72];
    __shared__ __align__(16) float  Wf[64][68];
    __shared__ float pads[64];
    __shared__ float red[4];
    __shared__ int   anyDeg;

    const int tid  = threadIdx.x;
    const int w    = tid >> 6;
    const int lane = tid & 63;
    const int g    = lane >> 4;
    const int c    = lane & 15;
    const int b    = blockIdx.x & 7;
    const int qt   = 63 - (blockIdx.x >> 3);
    const int q0   = qt * 64;

    if (tid == 0) anyDeg = 0;

    {
        const float* src = Qg + ((size_t)b * S_LEN + q0) * D_DIM;
        #pragma unroll
        for (int i = 0; i < 4; ++i) {
            int f4 = i * 256 + tid;
            int r  = f4 >> 4;
            int c4 = (f4 & 15) * 4;
            float4 v4 = *(const float4*)(src + (size_t)f4 * 4);
            bf16x4v bv;
            bv[0]=(bf16_t)v4.x; bv[1]=(bf16_t)v4.y; bv[2]=(bf16_t)v4.z; bv[3]=(bf16_t)v4.w;
            *(bf16x4v*)&Qs[r][c4] = bv;
        }
    }
    __syncthreads();

    bf16x8 qa[2];
    {
        int row = 16 * w + c;
        #pragma unroll
        for (int ks = 0; ks < 2; ++ks)
            qa[ks] = *(const bf16x8*)&Qs[row][ks * 32 + 8 * g];
    }

    float m[4], l[4];
    #pragma unroll
    for (int r = 0; r < 4; ++r) { m[r] = -INFINITY; l[r] = 0.f; }
    const int qgBase = q0 + 16 * w + 4 * g;

    for (int kt = 0; kt <= qt; ++kt) {
        const int k0 = kt * 64;
        {
            const float* src = Kg + ((size_t)b * S_LEN + k0) * D_DIM;
            #pragma unroll
            for (int i = 0; i < 4; ++i) {
                int f4 = i * 256 + tid;
                int r  = f4 >> 4;
                int c4 = (f4 & 15) * 4;
                float4 v4 = *(const float4*)(src + (size_t)f4 * 4);
                bf16x4v bv;
                bv[0]=(bf16_t)v4.x; bv[1]=(bf16_t)v4.y; bv[2]=(bf16_t)v4.z; bv[3]=(bf16_t)v4.w;
                *(bf16x4v*)&Ks[r][c4] = bv;
            }
            if (tid < 64) pads[tid] = Pg[(size_t)b * S_LEN + k0 + tid] * (-NEG_BIG);
        }
        __syncthreads();

        f32x4v sc[4];
        #pragma unroll
        for (int ct = 0; ct < 4; ++ct) {
            sc[ct] = (f32x4v){0.f, 0.f, 0.f, 0.f};
            #pragma unroll
            for (int ks = 0; ks < 2; ++ks) {
                bf16x8 kb = *(const bf16x8*)&Ks[ct * 16 + c][ks * 32 + 8 * g];
                sc[ct] = __builtin_amdgcn_mfma_f32_16x16x32_bf16(qa[ks], kb, sc[ct], 0, 0, 0);
            }
        }
        float l4[4][4];
        #pragma unroll
        for (int ct = 0; ct < 4; ++ct) {
            float pn  = pads[ct * 16 + c];
            int   kgi = k0 + ct * 16 + c;
            #pragma unroll
            for (int r = 0; r < 4; ++r) {
                float lg = sc[ct][r] * 0.125f + pn;
                if (kgi > qgBase + r) lg -= NEG_BIG;
                l4[ct][r] = lg;
            }
        }
        #pragma unroll
        for (int r = 0; r < 4; ++r) {
            float tm = fmaxf(fmaxf(l4[0][r], l4[1][r]), fmaxf(l4[2][r], l4[3][r]));
            tm = fmaxf(tm, __shfl_xor(tm, 1));
            tm = fmaxf(tm, __shfl_xor(tm, 2));
            tm = fmaxf(tm, __shfl_xor(tm, 4));
            tm = fmaxf(tm, __shfl_xor(tm, 8));
            float mnew = fmaxf(m[r], tm);
            float s = __expf(l4[0][r] - mnew) + __expf(l4[1][r] - mnew)
                    + __expf(l4[2][r] - mnew) + __expf(l4[3][r] - mnew);
            s += __shfl_xor(s, 1);
            s += __shfl_xor(s, 2);
            s += __shfl_xor(s, 4);
            s += __shfl_xor(s, 8);
            l[r] = l[r] * __expf(m[r] - mnew) + s;
            m[r] = mnew;
        }
        __syncthreads();
    }

    {
        float cnt = 0.f;
        const float* pb = Pg + (size_t)b * S_LEN;
        for (int i = tid; i < S_LEN; i += 256) cnt += 1.f - pb[i];
        #pragma unroll
        for (int off = 32; off >= 1; off >>= 1) cnt += __shfl_down(cnt, off);
        if (lane == 0) red[w] = cnt;
    }
    __syncthreads();
    {
        float nonpad = red[0] + red[1] + red[2] + red[3];
        bool deg = false;
        #pragma unroll
        for (int r = 0; r < 4; ++r)
            if (m[r] < -1.0e14f) { l[r] += nonpad; deg = true; }
        if (deg) anyDeg = 1;
    }
    __syncthreads();
    const bool blockDeg = (anyDeg != 0);
    float linv[4];
    #pragma unroll
    for (int r = 0; r < 4; ++r) linv[r] = 1.f / l[r];

    f32x4v o[4];
    #pragma unroll
    for (int dt = 0; dt < 4; ++dt) o[dt] = (f32x4v){0.f, 0.f, 0.f, 0.f};

    for (int kt = 0; kt < 64; ++kt) {
        const int k0 = kt * 64;
        float* wbase = Wg + (size_t)b * S_LEN * S_LEN + (size_t)q0 * S_LEN + k0;

        if (kt <= qt || blockDeg) {
            const float* ksrc = Kg + ((size_t)b * S_LEN + k0) * D_DIM;
            const float* vsrc = Vg + ((size_t)b * S_LEN + k0) * D_DIM;
            #pragma unroll
            for (int i = 0; i < 4; ++i) {
                int f4 = i * 256 + tid;
                int r  = f4 >> 4;
                int c4 = (f4 & 15) * 4;
                float4 kv = *(const float4*)(ksrc + (size_t)f4 * 4);
                bf16x4v bv;
                bv[0]=(bf16_t)kv.x; bv[1]=(bf16_t)kv.y; bv[2]=(bf16_t)kv.z; bv[3]=(bf16_t)kv.w;
                *(bf16x4v*)&Ks[r][c4] = bv;
                float4 vv = *(const float4*)(vsrc + (size_t)f4 * 4);
                VT[c4 + 0][r] = (bf16_t)vv.x;
                VT[c4 + 1][r] = (bf16_t)vv.y;
                VT[c4 + 2][r] = (bf16_t)vv.z;
                VT[c4 + 3][r] = (bf16_t)vv.w;
            }
            if (tid < 64) pads[tid] = Pg[(size_t)b * S_LEN + k0 + tid] * (-NEG_BIG);
            __syncthreads();

            f32x4v sc[4];
            #pragma unroll
            for (int ct = 0; ct < 4; ++ct) {
                sc[ct] = (f32x4v){0.f, 0.f, 0.f, 0.f};
                #pragma unroll
                for (int ks = 0; ks < 2; ++ks) {
                    bf16x8 kb = *(const bf16x8*)&Ks[ct * 16 + c][ks * 32 + 8 * g];
                    sc[ct] = __builtin_amdgcn_mfma_f32_16x16x32_bf16(qa[ks], kb, sc[ct], 0, 0, 0);
                }
            }
            #pragma unroll
            for (int ct = 0; ct < 4; ++ct) {
                float pn  = pads[ct * 16 + c];
                int   kgi = k0 + ct * 16 + c;
                #pragma unroll
                for (int r = 0; r < 4; ++r) {
                    float lg = sc[ct][r] * 0.125f + pn;
                    if (kgi > qgBase + r) lg -= NEG_BIG;
                    float wv = __expf(lg - m[r]) * linv[r];
                    Wf[16 * w + 4 * g + r][ct * 16 + c] = wv;
                }
            }
            __syncthreads();

            #pragma unroll
            for (int i = 0; i < 4; ++i) {
                int f4 = i * 256 + tid;
                int r  = f4 >> 4;
                int c4 = (f4 & 15) * 4;
                float4 wv = *(const float4*)&Wf[r][c4];
                *(float4*)(wbase + (size_t)r * S_LEN + c4) = wv;
            }

            #pragma unroll
            for (int ks = 0; ks < 2; ++ks) {
                float4 f0 = *(const float4*)&Wf[16 * w + c][ks * 32 + 8 * g];
                float4 f1 = *(const float4*)&Wf[16 * w + c][ks * 32 + 8 * g + 4];
                bf16x8 wa;
                wa[0]=(bf16_t)f0.x; wa[1]=(bf16_t)f0.y; wa[2]=(bf16_t)f0.z; wa[3]=(bf16_t)f0.w;
                wa[4]=(bf16_t)f1.x; wa[5]=(bf16_t)f1.y; wa[6]=(bf16_t)f1.z; wa[7]=(bf16_t)f1.w;
                #pragma unroll
                for (int dt = 0; dt < 4; ++dt) {
                    bf16x8 vb = *(const bf16x8*)&VT[dt * 16 + c][ks * 32 + 8 * g];
                    o[dt] = __builtin_amdgcn_mfma_f32_16x16x32_bf16(wa, vb, o[dt], 0, 0, 0);
                }
            }
            __syncthreads();
        } else {
            const float4 z = {0.f, 0.f, 0.f, 0.f};
            #pragma unroll
            for (int i = 0; i < 4; ++i) {
                int f4 = i * 256 + tid;
                int r  = f4 >> 4;
                int c4 = (f4 & 15) * 4;
                *(float4*)(wbase + (size_t)r * S_LEN + c4) = z;
            }
        }
    }

    #pragma unroll
    for (int dt = 0; dt < 4; ++dt)
        #pragma unroll
        for (int r = 0; r < 4; ++r)
            Og[((size_t)b * S_LEN + (q0 + 16 * w + 4 * g + r)) * D_DIM + dt * 16 + c] = o[dt][r];
}

extern "C" void kernel_launch(void* const* d_in, const int* in_sizes, int n_in,
                              void* d_out, int out_size, void* d_ws, size_t ws_size,
                              hipStream_t stream) {
    const float* q   = (const float*)d_in[0];
    const float* k   = (const float*)d_in[1];
    const float* v   = (const float*)d_in[2];
    const float* pad = (const float*)d_in[3];

    float* out  = (float*)d_out;
    float* ctx  = out;
    float* attw = out + (size_t)8 * 4096 * 64;
    float* ws   = (float*)d_ws;

    if (ws_size >= (size_t)WS_FLOATS_NEEDED * 4) {
        hipLaunchKernelGGL(sdpa_prep, dim3(8), dim3(256), 0, stream, pad, ws);
        hipLaunchKernelGGL(sdpa_main, dim3(8192), dim3(256), 0, stream,
                           q, k, v, pad, attw, ws, ctx);
    } else {
        hipLaunchKernelGGL(sdpa_fused, dim3(512), dim3(256), 0, stream, q, k, v, pad, ctx, attw);
    }
}

// Round 10
// 171.243 us; speedup vs baseline: 3.3256x; 3.3256x over previous
//
#include <hip/hip_runtime.h>

#define S_LEN 4096
#define D_DIM 64
#define NEG_BIG 1.0e15f
#define NC1 8          // k-chunks (8 tiles each)
#define SSTAT (8 * 64 * NC1 * 64)           // floats: [b][qt][kc][64] row partial sums
#define NPAD_OFF SSTAT                      // [0..7]=npadTot, [8..15]=firstNonPad
#define WS_FLOATS_NEEDED (NPAD_OFF + 16)
#define VSTRIDE 70     // odd word-stride: transpose u16 writes ~conflict-free

typedef __bf16 bf16_t;
typedef bf16_t bf16x8 __attribute__((ext_vector_type(8)));
typedef bf16_t bf16x4v __attribute__((ext_vector_type(4)));
typedef bf16_t bf16x2v __attribute__((ext_vector_type(2)));
typedef float f32x4v __attribute__((ext_vector_type(4)));

// ---------------- kernel 0: prep — per-batch npadTot and firstNonPad ----------
__global__ void sdpa_prep(const float* __restrict__ Pg, float* __restrict__ ws)
{
    __shared__ float red[16];
    const int b   = blockIdx.x;          // 8 blocks
    const int tid = threadIdx.x;

    float cnt = 0.f, first = (float)S_LEN;
    const float* pb = Pg + (size_t)b * S_LEN;
    for (int i = tid; i < S_LEN; i += 256) {
        float p = pb[i];
        cnt += 1.f - p;
        if (p == 0.f) first = fminf(first, (float)i);
    }
    #pragma unroll
    for (int off = 32; off >= 1; off >>= 1) {
        cnt += __shfl_down(cnt, off);
        first = fminf(first, __shfl_down(first, off));
    }
    const int w = tid >> 6, lane = tid & 63;
    if (lane == 0) { red[w] = cnt; red[8 + w] = first; }
    __syncthreads();
    if (tid == 0) {
        ws[NPAD_OFF + b]     = red[0] + red[1] + red[2] + red[3];
        ws[NPAD_OFF + 8 + b] = fminf(fminf(red[8], red[9]), fminf(red[10], red[11]));
    }
}

// ---------------- kernel 1: denominators + zero-fill of future W region -------
// Stats is compute/latency-bound with an idle store pipe: each chunk (b,qt,kc)
// also zero-fills future k-tiles {qt+1+kc+8j} of its q-tile (non-deg tiles only;
// deg q-tiles are fully written by wpv). Union over kc covers (qt,63] exactly.
__global__ __launch_bounds__(256, 2)
void sdpa_stats(const float* __restrict__ Qg,
                const float* __restrict__ Kg,
                const float* __restrict__ Pg,
                float* __restrict__ ws,
                float* __restrict__ ctx,
                float* __restrict__ Wg)
{
    __shared__ __align__(16) bf16_t Ks[64][72];
    __shared__ float pads[64];

    const int tid  = threadIdx.x;
    const int w    = tid >> 6;
    const int lane = tid & 63;
    const int g    = lane >> 4;
    const int c    = lane & 15;
    const int gx   = blockIdx.x;
    const int b    = gx & 7;            // batch -> XCD pinning (load-bearing!)
    const int t    = gx >> 3;
    const int qt   = 63 - (t & 63);     // qt descending within each kc
    const int kc   = t >> 6;
    const int q0   = qt * 64;

    // ctx zeroing spread over the later-launched half of the grid
    if (gx >= 2048) {
        f32x4v z = {0.f, 0.f, 0.f, 0.f};
        *(f32x4v*)(ctx + (size_t)(gx - 2048) * 1024 + tid * 4) = z;
    }

    const int firstNP = (int)ws[NPAD_OFF + 8 + b];

    // ---- zero-fill our share of the future W tiles (issued early; drains
    //      under the QK^T compute below) ----
    if (q0 >= firstNP) {                // non-deg q-tile (deg ones: wpv covers all)
        const f32x4v z = {0.f, 0.f, 0.f, 0.f};
        float* wrow = Wg + (size_t)b * S_LEN * S_LEN + (size_t)q0 * S_LEN;
        for (int fz = qt + 1 + kc; fz < 64; fz += 8) {
            float* wbase = wrow + fz * 64;
            #pragma unroll
            for (int i = 0; i < 4; ++i) {
                int f4 = i * 256 + tid;
                int r  = f4 >> 4;
                int c4 = (f4 & 15) * 4;
                __builtin_nontemporal_store(z, (f32x4v*)(wbase + (size_t)r * S_LEN + c4));
            }
        }
    }

    if (kc * 8 > qt) return;            // trivial chunk: wpv sums only `need` chunks

    // Q fragments direct from global (row 16w+c, d = 8g+j+32ks)
    bf16x8 qa[2];
    {
        const float* qrow = Qg + ((size_t)b * S_LEN + q0 + 16 * w + c) * D_DIM;
        #pragma unroll
        for (int ks = 0; ks < 2; ++ks) {
            float4 a0 = *(const float4*)(qrow + ks * 32 + 8 * g);
            float4 a1 = *(const float4*)(qrow + ks * 32 + 8 * g + 4);
            qa[ks][0]=(bf16_t)a0.x; qa[ks][1]=(bf16_t)a0.y; qa[ks][2]=(bf16_t)a0.z; qa[ks][3]=(bf16_t)a0.w;
            qa[ks][4]=(bf16_t)a1.x; qa[ks][5]=(bf16_t)a1.y; qa[ks][6]=(bf16_t)a1.z; qa[ks][7]=(bf16_t)a1.w;
        }
    }

    float l[4] = {0.f, 0.f, 0.f, 0.f};
    const int qgBase = q0 + 16 * w + 4 * g;
    const int kend = min(kc * 8 + 8, qt + 1);

    for (int kt = kc * 8; kt < kend; ++kt) {
        const int k0 = kt * 64;
        {
            const float* src = Kg + ((size_t)b * S_LEN + k0) * D_DIM;
            #pragma unroll
            for (int i = 0; i < 4; ++i) {
                int f4 = i * 256 + tid;
                int r  = f4 >> 4;
                int c4 = (f4 & 15) * 4;
                float4 v4 = *(const float4*)(src + (size_t)f4 * 4);
                bf16x4v bv;
                bv[0]=(bf16_t)v4.x; bv[1]=(bf16_t)v4.y; bv[2]=(bf16_t)v4.z; bv[3]=(bf16_t)v4.w;
                *(bf16x4v*)&Ks[r][c4] = bv;
            }
            if (tid < 64) pads[tid] = Pg[(size_t)b * S_LEN + k0 + tid] * (-NEG_BIG);
        }
        __syncthreads();

        f32x4v sc[4];
        #pragma unroll
        for (int ct = 0; ct < 4; ++ct) {
            sc[ct] = (f32x4v){0.f, 0.f, 0.f, 0.f};
            #pragma unroll
            for (int ks = 0; ks < 2; ++ks) {
                bf16x8 kb = *(const bf16x8*)&Ks[ct * 16 + c][ks * 32 + 8 * g];
                sc[ct] = __builtin_amdgcn_mfma_f32_16x16x32_bf16(qa[ks], kb, sc[ct], 0, 0, 0);
            }
        }
        // no max tracking: exp(-1e15)=0 handles masks; logits are O(5).
        // deferred reduce: per-lane accumulation, one shuffle-reduce at the end.
        #pragma unroll
        for (int ct = 0; ct < 4; ++ct) {
            float pn  = pads[ct * 16 + c];
            int   kgi = k0 + ct * 16 + c;
            #pragma unroll
            for (int r = 0; r < 4; ++r) {
                float lg = sc[ct][r] * 0.125f + pn;
                if (kgi > qgBase + r) lg -= NEG_BIG;
                l[r] += __expf(lg);
            }
        }
        __syncthreads();
    }

    const size_t soff = ((size_t)((b * 64 + qt) * NC1 + kc)) * 64;
    #pragma unroll
    for (int r = 0; r < 4; ++r) {
        float s = l[r];
        s += __shfl_xor(s, 1);
        s += __shfl_xor(s, 2);
        s += __shfl_xor(s, 4);
        s += __shfl_xor(s, 8);
        l[r] = s;
    }
    if (c == 0) {
        #pragma unroll
        for (int r = 0; r < 4; ++r)
            ws[soff + 16 * w + 4 * g + r] = l[r];
    }
}

// ---------------- kernel 2: causal W tiles (nt) + PV atomics into ctx ---------
// Future region already zero-filled by sdpa_stats (except deg q-tiles, handled
// here by the blockDeg full-range loop — overlapping writes are identical 0.0).
__global__ __launch_bounds__(256, 2)
void sdpa_wpv(const float* __restrict__ Qg,
              const float* __restrict__ Kg,
              const float* __restrict__ Vg,
              const float* __restrict__ Pg,
              float* __restrict__ Wg,
              float* __restrict__ ws,
              float* __restrict__ ctx)
{
    __shared__ __align__(16) bf16_t Ks[64][72];
    __shared__ __align__(16) bf16_t VT[64][VSTRIDE];   // VT[d][k_local]
    __shared__ __align__(16) bf16_t Pf[64][72];        // bf16 weights; per-wave rows only
    __shared__ float pads[64];
    __shared__ float Lrow[64];

    const int tid  = threadIdx.x;
    const int w    = tid >> 6;
    const int lane = tid & 63;
    const int g    = lane >> 4;
    const int c    = lane & 15;
    const int gx   = blockIdx.x;
    const int b    = gx & 7;            // XCD pinning
    const int t    = gx >> 3;
    const int qt   = 63 - (t & 63);
    const int kc   = t >> 6;
    const int q0   = qt * 64;
    const int kstart = kc * 8;

    const float npadTot = ws[NPAD_OFF + b];
    const int   firstNP = (int)ws[NPAD_OFF + 8 + b];
    const bool  blockDeg = (q0 < firstNP);   // tile contains degenerate rows

    if (kstart > qt && !blockDeg) return;    // future chunk: stats zero-filled it

    // combine partial denominators (deg rows: closed-form count)
    if (tid < 64) {
        int qrow = q0 + tid;
        float L;
        if (qrow < firstNP) {
            L = (float)(qrow + 1) + npadTot;  // #causal(all padded) + #future nonpad
        } else {
            const float* sb = ws + (size_t)(b * 64 + qt) * NC1 * 64 + tid;
            L = 0.f;
            const int need = (qt >> 3) + 1;
            for (int i = 0; i < need; ++i) L += sb[(size_t)i * 64];
        }
        Lrow[tid] = 1.f / L;
    }
    __syncthreads();

    float* wchunk = Wg + (size_t)b * S_LEN * S_LEN + (size_t)q0 * S_LEN;

    // Q fragments direct from global (L2-resident across kc-chunks)
    bf16x8 qa[2];
    {
        const float* qrow = Qg + ((size_t)b * S_LEN + q0 + 16 * w + c) * D_DIM;
        #pragma unroll
        for (int ks = 0; ks < 2; ++ks) {
            float4 a0 = *(const float4*)(qrow + ks * 32 + 8 * g);
            float4 a1 = *(const float4*)(qrow + ks * 32 + 8 * g + 4);
            qa[ks][0]=(bf16_t)a0.x; qa[ks][1]=(bf16_t)a0.y; qa[ks][2]=(bf16_t)a0.z; qa[ks][3]=(bf16_t)a0.w;
            qa[ks][4]=(bf16_t)a1.x; qa[ks][5]=(bf16_t)a1.y; qa[ks][6]=(bf16_t)a1.z; qa[ks][7]=(bf16_t)a1.w;
        }
    }

    const int qgBase = q0 + 16 * w + 4 * g;
    float linv[4];
    #pragma unroll
    for (int r = 0; r < 4; ++r) linv[r] = Lrow[16 * w + 4 * g + r];

    f32x4v o[4];
    #pragma unroll
    for (int dt = 0; dt < 4; ++dt) o[dt] = (f32x4v){0.f, 0.f, 0.f, 0.f};

    // non-deg: only causal tiles (future handled by stats); deg: all 8 tiles
    const int kend2 = blockDeg ? (kstart + 8) : min(kstart + 8, qt + 1);

    for (int kt = kstart; kt < kend2; ++kt) {
        const int k0 = kt * 64;
        float* wbase = wchunk + k0;

        const float* ksrc = Kg + ((size_t)b * S_LEN + k0) * D_DIM;
        const float* vsrc = Vg + ((size_t)b * S_LEN + k0) * D_DIM;
        #pragma unroll
        for (int i = 0; i < 4; ++i) {
            int f4 = i * 256 + tid;
            int r  = f4 >> 4;
            int c4 = (f4 & 15) * 4;
            float4 kv = *(const float4*)(ksrc + (size_t)f4 * 4);
            bf16x4v bv;
            bv[0]=(bf16_t)kv.x; bv[1]=(bf16_t)kv.y; bv[2]=(bf16_t)kv.z; bv[3]=(bf16_t)kv.w;
            *(bf16x4v*)&Ks[r][c4] = bv;
            float4 vv = *(const float4*)(vsrc + (size_t)f4 * 4);
            VT[c4 + 0][r] = (bf16_t)vv.x;
            VT[c4 + 1][r] = (bf16_t)vv.y;
            VT[c4 + 2][r] = (bf16_t)vv.z;
            VT[c4 + 3][r] = (bf16_t)vv.w;
        }
        if (tid < 64) pads[tid] = Pg[(size_t)b * S_LEN + k0 + tid] * (-NEG_BIG);
        __syncthreads();

        f32x4v sc[4];
        #pragma unroll
        for (int ct = 0; ct < 4; ++ct) {
            sc[ct] = (f32x4v){0.f, 0.f, 0.f, 0.f};
            #pragma unroll
            for (int ks = 0; ks < 2; ++ks) {
                bf16x8 kb = *(const bf16x8*)&Ks[ct * 16 + c][ks * 32 + 8 * g];
                sc[ct] = __builtin_amdgcn_mfma_f32_16x16x32_bf16(qa[ks], kb, sc[ct], 0, 0, 0);
            }
        }
        if (!blockDeg) {
            #pragma unroll
            for (int ct = 0; ct < 4; ++ct) {
                float pn  = pads[ct * 16 + c];
                int   kgi = k0 + ct * 16 + c;
                #pragma unroll
                for (int r = 0; r < 4; ++r) {
                    float lg = sc[ct][r] * 0.125f + pn;
                    if (kgi > qgBase + r) lg -= NEG_BIG;
                    float wv = __expf(lg) * linv[r];        // == ref weight
                    __builtin_nontemporal_store(wv,
                        wbase + (size_t)(16 * w + 4 * g + r) * S_LEN + ct * 16 + c);
                    Pf[16 * w + 4 * g + r][ct * 16 + c] = (bf16_t)wv;
                }
            }
        } else {
            #pragma unroll
            for (int ct = 0; ct < 4; ++ct) {
                float pn  = pads[ct * 16 + c];
                int   kgi = k0 + ct * 16 + c;
                #pragma unroll
                for (int r = 0; r < 4; ++r) {
                    float lg = sc[ct][r] * 0.125f + pn;
                    if (kgi > qgBase + r) lg -= NEG_BIG;
                    float wv = __expf(lg) * linv[r];
                    if (qgBase + r < firstNP)               // degenerate row
                        wv = (kgi <= qgBase + r || pn == 0.f) ? linv[r] : 0.f;
                    __builtin_nontemporal_store(wv,
                        wbase + (size_t)(16 * w + 4 * g + r) * S_LEN + ct * 16 + c);
                    Pf[16 * w + 4 * g + r][ct * 16 + c] = (bf16_t)wv;
                }
            }
        }
        // NO barrier: wave w reads only its own Pf rows (lgkmcnt orders within-wave);
        // VT covered by post-stage barrier. W-store drain overlaps PV MFMAs.

        #pragma unroll
        for (int ks = 0; ks < 2; ++ks) {
            bf16x8 wa = *(const bf16x8*)&Pf[16 * w + c][ks * 32 + 8 * g];
            #pragma unroll
            for (int dt = 0; dt < 4; ++dt) {
                bf16x8 vb;
                #pragma unroll
                for (int p = 0; p < 4; ++p)
                    ((bf16x2v*)&vb)[p] = *(const bf16x2v*)&VT[dt * 16 + c][ks * 32 + 8 * g + 2 * p];
                o[dt] = __builtin_amdgcn_mfma_f32_16x16x32_bf16(wa, vb, o[dt], 0, 0, 0);
            }
        }
        __syncthreads();   // protect Ks/VT/Pf before next-tile staging
    }

    // accumulate partial PV straight into ctx (zeroed by sdpa_stats)
    #pragma unroll
    for (int dt = 0; dt < 4; ++dt)
        #pragma unroll
        for (int r = 0; r < 4; ++r)
            atomicAdd(&ctx[((size_t)b * S_LEN + (q0 + 16 * w + 4 * g + r)) * D_DIM + dt * 16 + c],
                      o[dt][r]);
}

// ---------------- fallback: monolithic kernel (used only if ws too small) ----
__global__ __launch_bounds__(256, 2)
void sdpa_fused(const float* __restrict__ Qg,
                const float* __restrict__ Kg,
                const float* __restrict__ Vg,
                const float* __restrict__ Pg,
                float* __restrict__ Og,
                float* __restrict__ Wg)
{
    __shared__ __align__(16) bf16_t Qs[64][72];
    __shared__ __align__(16) bf16_t Ks[64][72];
    __shared__ __align__(16) bf16_t VT[64][72];
    __shared__ __align__(16) float  Wf[64][68];
    __shared__ float pads[64];
    __shared__ float red[4];
    __shared__ int   anyDeg;

    const int tid  = threadIdx.x;
    const int w    = tid >> 6;
    const int lane = tid & 63;
    const int g    = lane >> 4;
    const int c    = lane & 15;
    const int b    = blockIdx.x & 7;
    const int qt   = 63 - (blockIdx.x >> 3);
    const int q0   = qt * 64;

    if (tid == 0) anyDeg = 0;

    {
        const float* src = Qg + ((size_t)b * S_LEN + q0) * D_DIM;
        #pragma unroll
        for (int i = 0; i < 4; ++i) {
            int f4 = i * 256 + tid;
            int r  = f4 >> 4;
            int c4 = (f4 & 15) * 4;
            float4 v4 = *(const float4*)(src + (size_t)f4 * 4);
            bf16x4v bv;
            bv[0]=(bf16_t)v4.x; bv[1]=(bf16_t)v4.y; bv[2]=(bf16_t)v4.z; bv[3]=(bf16_t)v4.w;
            *(bf16x4v*)&Qs[r][c4] = bv;
        }
    }
    __syncthreads();

    bf16x8 qa[2];
    {
        int row = 16 * w + c;
        #pragma unroll
        for (int ks = 0; ks < 2; ++ks)
            qa[ks] = *(const bf16x8*)&Qs[row][ks * 32 + 8 * g];
    }

    float m[4], l[4];
    #pragma unroll
    for (int r = 0; r < 4; ++r) { m[r] = -INFINITY; l[r] = 0.f; }
    const int qgBase = q0 + 16 * w + 4 * g;

    for (int kt = 0; kt <= qt; ++kt) {
        const int k0 = kt * 64;
        {
            const float* src = Kg + ((size_t)b * S_LEN + k0) * D_DIM;
            #pragma unroll
            for (int i = 0; i < 4; ++i) {
                int f4 = i * 256 + tid;
                int r  = f4 >> 4;
                int c4 = (f4 & 15) * 4;
                float4 v4 = *(const float4*)(src + (size_t)f4 * 4);
                bf16x4v bv;
                bv[0]=(bf16_t)v4.x; bv[1]=(bf16_t)v4.y; bv[2]=(bf16_t)v4.z; bv[3]=(bf16_t)v4.w;
                *(bf16x4v*)&Ks[r][c4] = bv;
            }
            if (tid < 64) pads[tid] = Pg[(size_t)b * S_LEN + k0 + tid] * (-NEG_BIG);
        }
        __syncthreads();

        f32x4v sc[4];
        #pragma unroll
        for (int ct = 0; ct < 4; ++ct) {
            sc[ct] = (f32x4v){0.f, 0.f, 0.f, 0.f};
            #pragma unroll
            for (int ks = 0; ks < 2; ++ks) {
                bf16x8 kb = *(const bf16x8*)&Ks[ct * 16 + c][ks * 32 + 8 * g];
                sc[ct] = __builtin_amdgcn_mfma_f32_16x16x32_bf16(qa[ks], kb, sc[ct], 0, 0, 0);
            }
        }
        float l4[4][4];
        #pragma unroll
        for (int ct = 0; ct < 4; ++ct) {
            float pn  = pads[ct * 16 + c];
            int   kgi = k0 + ct * 16 + c;
            #pragma unroll
            for (int r = 0; r < 4; ++r) {
                float lg = sc[ct][r] * 0.125f + pn;
                if (kgi > qgBase + r) lg -= NEG_BIG;
                l4[ct][r] = lg;
            }
        }
        #pragma unroll
        for (int r = 0; r < 4; ++r) {
            float tm = fmaxf(fmaxf(l4[0][r], l4[1][r]), fmaxf(l4[2][r], l4[3][r]));
            tm = fmaxf(tm, __shfl_xor(tm, 1));
            tm = fmaxf(tm, __shfl_xor(tm, 2));
            tm = fmaxf(tm, __shfl_xor(tm, 4));
            tm = fmaxf(tm, __shfl_xor(tm, 8));
            float mnew = fmaxf(m[r], tm);
            float s = __expf(l4[0][r] - mnew) + __expf(l4[1][r] - mnew)
                    + __expf(l4[2][r] - mnew) + __expf(l4[3][r] - mnew);
            s += __shfl_xor(s, 1);
            s += __shfl_xor(s, 2);
            s += __shfl_xor(s, 4);
            s += __shfl_xor(s, 8);
            l[r] = l[r] * __expf(m[r] - mnew) + s;
            m[r] = mnew;
        }
        __syncthreads();
    }

    {
        float cnt = 0.f;
        const float* pb = Pg + (size_t)b * S_LEN;
        for (int i = tid; i < S_LEN; i += 256) cnt += 1.f - pb[i];
        #pragma unroll
        for (int off = 32; off >= 1; off >>= 1) cnt += __shfl_down(cnt, off);
        if (lane == 0) red[w] = cnt;
    }
    __syncthreads();
    {
        float nonpad = red[0] + red[1] + red[2] + red[3];
        bool deg = false;
        #pragma unroll
        for (int r = 0; r < 4; ++r)
            if (m[r] < -1.0e14f) { l[r] += nonpad; deg = true; }
        if (deg) anyDeg = 1;
    }
    __syncthreads();
    const bool blockDeg = (anyDeg != 0);
    float linv[4];
    #pragma unroll
    for (int r = 0; r < 4; ++r) linv[r] = 1.f / l[r];

    f32x4v o[4];
    #pragma unroll
    for (int dt = 0; dt < 4; ++dt) o[dt] = (f32x4v){0.f, 0.f, 0.f, 0.f};

    for (int kt = 0; kt < 64; ++kt) {
        const int k0 = kt * 64;
        float* wbase = Wg + (size_t)b * S_LEN * S_LEN + (size_t)q0 * S_LEN + k0;

        if (kt <= qt || blockDeg) {
            const float* ksrc = Kg + ((size_t)b * S_LEN + k0) * D_DIM;
            const float* vsrc = Vg + ((size_t)b * S_LEN + k0) * D_DIM;
            #pragma unroll
            for (int i = 0; i < 4; ++i) {
                int f4 = i * 256 + tid;
                int r  = f4 >> 4;
                int c4 = (f4 & 15) * 4;
                float4 kv = *(const float4*)(ksrc + (size_t)f4 * 4);
                bf16x4v bv;
                bv[0]=(bf16_t)kv.x; bv[1]=(bf16_t)kv.y; bv[2]=(bf16_t)kv.z; bv[3]=(bf16_t)kv.w;
                *(bf16x4v*)&Ks[r][c4] = bv;
                float4 vv = *(const float4*)(vsrc + (size_t)f4 * 4);
                VT[c4 + 0][r] = (bf16_t)vv.x;
                VT[c4 + 1][r] = (bf16_t)vv.y;
                VT[c4 + 2][r] = (bf16_t)vv.z;
                VT[c4 + 3][r] = (bf16_t)vv.w;
            }
            if (tid < 64) pads[tid] = Pg[(size_t)b * S_LEN + k0 + tid] * (-NEG_BIG);
            __syncthreads();

            f32x4v sc[4];
            #pragma unroll
            for (int ct = 0; ct < 4; ++ct) {
                sc[ct] = (f32x4v){0.f, 0.f, 0.f, 0.f};
                #pragma unroll
                for (int ks = 0; ks < 2; ++ks) {
                    bf16x8 kb = *(const bf16x8*)&Ks[ct * 16 + c][ks * 32 + 8 * g];
                    sc[ct] = __builtin_amdgcn_mfma_f32_16x16x32_bf16(qa[ks], kb, sc[ct], 0, 0, 0);
                }
            }
            #pragma unroll
            for (int ct = 0; ct < 4; ++ct) {
                float pn  = pads[ct * 16 + c];
                int   kgi = k0 + ct * 16 + c;
                #pragma unroll
                for (int r = 0; r < 4; ++r) {
                    float lg = sc[ct][r] * 0.125f + pn;
                    if (kgi > qgBase + r) lg -= NEG_BIG;
                    float wv = __expf(lg - m[r]) * linv[r];
                    Wf[16 * w + 4 * g + r][ct * 16 + c] = wv;
                }
            }
            __syncthreads();

            #pragma unroll
            for (int i = 0; i < 4; ++i) {
                int f4 = i * 256 + tid;
                int r  = f4 >> 4;
                int c4 = (f4 & 15) * 4;
                float4 wv = *(const float4*)&Wf[r][c4];
                *(float4*)(wbase + (size_t)r * S_LEN + c4) = wv;
            }

            #pragma unroll
            for (int ks = 0; ks < 2; ++ks) {
                float4 f0 = *(const float4*)&Wf[16 * w + c][ks * 32 + 8 * g];
                float4 f1 = *(const float4*)&Wf[16 * w + c][ks * 32 + 8 * g + 4];
                bf16x8 wa;
                wa[0]=(bf16_t)f0.x; wa[1]=(bf16_t)f0.y; wa[2]=(bf16_t)f0.z; wa[3]=(bf16_t)f0.w;
                wa[4]=(bf16_t)f1.x; wa[5]=(bf16_t)f1.y; wa[6]=(bf16_t)f1.z; wa[7]=(bf16_t)f1.w;
                #pragma unroll
                for (int dt = 0; dt < 4; ++dt) {
                    bf16x8 vb = *(const bf16x8*)&VT[dt * 16 + c][ks * 32 + 8 * g];
                    o[dt] = __builtin_amdgcn_mfma_f32_16x16x32_bf16(wa, vb, o[dt], 0, 0, 0);
                }
            }
            __syncthreads();
        } else {
            const float4 z = {0.f, 0.f, 0.f, 0.f};
            #pragma unroll
            for (int i = 0; i < 4; ++i) {
                int f4 = i * 256 + tid;
                int r  = f4 >> 4;
                int c4 = (f4 & 15) * 4;
                *(float4*)(wbase + (size_t)r * S_LEN + c4) = z;
            }
        }
    }

    #pragma unroll
    for (int dt = 0; dt < 4; ++dt)
        #pragma unroll
        for (int r = 0; r < 4; ++r)
            Og[((size_t)b * S_LEN + (q0 + 16 * w + 4 * g + r)) * D_DIM + dt * 16 + c] = o[dt][r];
}

extern "C" void kernel_launch(void* const* d_in, const int* in_sizes, int n_in,
                              void* d_out, int out_size, void* d_ws, size_t ws_size,
                              hipStream_t stream) {
    const float* q   = (const float*)d_in[0];
    const float* k   = (const float*)d_in[1];
    const float* v   = (const float*)d_in[2];
    const float* pad = (const float*)d_in[3];

    float* out  = (float*)d_out;
    float* ctx  = out;
    float* attw = out + (size_t)8 * 4096 * 64;
    float* ws   = (float*)d_ws;

    if (ws_size >= (size_t)WS_FLOATS_NEEDED * 4) {
        hipLaunchKernelGGL(sdpa_prep,  dim3(8),    dim3(256), 0, stream, pad, ws);
        hipLaunchKernelGGL(sdpa_stats, dim3(4096), dim3(256), 0, stream, q, k, pad, ws, ctx, attw);
        hipLaunchKernelGGL(sdpa_wpv,   dim3(4096), dim3(256), 0, stream, q, k, v, pad, attw, ws, ctx);
    } else {
        hipLaunchKernelGGL(sdpa_fused, dim3(512), dim3(256), 0, stream, q, k, v, pad, ctx, attw);
    }
}